// Round 7
// baseline (171.322 us; speedup 1.0000x reference)
//
#include <hip/hip_runtime.h>

// N=512, D=512 pairwise scorer, all f32.
// left = E@W1[:D]; right = E@W1[D:]+b1; h = left[i]+right[j]; LN(D); GELU; @W2+b2; sigmoid.
// LN stats decompose: var = var_l[i]+var_r[j]+2*cov(i,j), cov = (1/D) lc@rc^T (centered).
// Never materialize [N,N,D]. Upper-triangle 16x16 pair tiles, mirrored store.

#define N_ 512
#define D_ 512

// ---------------- K1: left/right GEMMs ----------------
// 512 blocks = 32 rowgrps (16 rows) x 16 ccgrps (64 combined cols of 1024).
// 256 thr: cq = t&15 (col quad), r = t>>4 (row). 1 row x 4 cols x 512 k each.
// e-row reads are phase-broadcast (8 lanes same addr) -> conflict-free.
// W1 L2 traffic: 64 cols*512k*4B*512 blocks = 64MB (~2us BW floor). 2 blocks/CU.
__global__ __launch_bounds__(256) void k_gemm(const float* __restrict__ E,
                                              const float* __restrict__ W1,
                                              const float* __restrict__ b1,
                                              float* __restrict__ W /* [1024][512] */) {
    __shared__ float e[16 * 516];
    const int t = threadIdx.x;
    const int cc = (blockIdx.x & 15) * 64;     // combined col base
    const int r0 = (blockIdx.x >> 4) * 16;
    const int half = cc >> 9;
    const int c = (cc & 511) + (t & 15) * 4;
    const int r = t >> 4;

    for (int x = t; x < 16 * 128; x += 256) {
        int rr = x >> 7, q = x & 127;
        *(float4*)&e[rr * 516 + q * 4] = *(const float4*)&E[(r0 + rr) * D_ + q * 4];
    }
    __syncthreads();

    const float* __restrict__ wp = W1 + (half << 18) + c;
    float4 acc = {0.f, 0.f, 0.f, 0.f};
#pragma unroll 4
    for (int k = 0; k < D_; k += 4) {
        float4 e4 = *(float4*)&e[r * 516 + k];
        float4 wa = *(const float4*)(wp + ((k + 0) << 9));
        float4 wb = *(const float4*)(wp + ((k + 1) << 9));
        float4 wc = *(const float4*)(wp + ((k + 2) << 9));
        float4 wd = *(const float4*)(wp + ((k + 3) << 9));
        acc.x = fmaf(e4.x, wa.x, acc.x); acc.y = fmaf(e4.x, wa.y, acc.y);
        acc.z = fmaf(e4.x, wa.z, acc.z); acc.w = fmaf(e4.x, wa.w, acc.w);
        acc.x = fmaf(e4.y, wb.x, acc.x); acc.y = fmaf(e4.y, wb.y, acc.y);
        acc.z = fmaf(e4.y, wb.z, acc.z); acc.w = fmaf(e4.y, wb.w, acc.w);
        acc.x = fmaf(e4.z, wc.x, acc.x); acc.y = fmaf(e4.z, wc.y, acc.y);
        acc.z = fmaf(e4.z, wc.z, acc.z); acc.w = fmaf(e4.z, wc.w, acc.w);
        acc.x = fmaf(e4.w, wd.x, acc.x); acc.y = fmaf(e4.w, wd.y, acc.y);
        acc.z = fmaf(e4.w, wd.z, acc.z); acc.w = fmaf(e4.w, wd.w, acc.w);
    }
    if (half) {
        float4 bb = *(const float4*)(b1 + c);
        acc.x += bb.x; acc.y += bb.y; acc.z += bb.z; acc.w += bb.w;
    }
    *(float4*)(W + ((half << 9) + r0 + r) * D_ + c) = acc;
}

// ---------------- K2: center rows, per-row variance ----------------
__device__ __forceinline__ float block_sum(float v, float* sred, int t) {
#pragma unroll
    for (int off = 32; off > 0; off >>= 1) v += __shfl_xor(v, off, 64);
    int wave = t >> 6;
    if ((t & 63) == 0) sred[wave] = v;
    __syncthreads();
    float s = sred[0] + sred[1] + sred[2] + sred[3];
    __syncthreads();
    return s;
}

__global__ __launch_bounds__(256) void k_center(float* __restrict__ W,
                                                float* __restrict__ var) {
    __shared__ float sred[4];
    const int r = blockIdx.x, t = threadIdx.x;
    float* p = W + r * D_;
    float v0 = p[t], v1 = p[t + 256];
    float s = block_sum(v0 + v1, sred, t);
    float mean = s * (1.f / D_);
    float c0 = v0 - mean, c1 = v1 - mean;
    float ss = block_sum(c0 * c0 + c1 * c1, sred, t);
    p[t] = c0;
    p[t + 256] = c1;
    if (t == 0) var[r] = ss * (1.f / D_);
}

// ---------------- K3: fused cov -> rstd -> gelu-dot -> sigmoid ----------------
// 528 blocks = upper-triangle 16x16 pair tiles. 256 thr:
//   lane l = t&63: pt = l&15 (4x4 pair block: pi=pt&3, pj=pt>>2), s = l>>4.
//   k-slice sigma = (t>>6)*4 + s owns quads Q = 16m + sigma (m=0..7).
// LDS: ls/rs [16][130] (stride 130 = 2 mod 32: rows d,4+d,8+d,12+d -> 4 distinct
// bank groups; slices add 4s -> phase-checked 2-way max = free). Chunked k=128,
// staged once per chunk per pass. red[16][257] overlays ls/rs (used only after
// staging done); pair index transposed (p' = j*16+i) -> conflict-free writes.
// ~17.7KB LDS, 16 chains/thread.
__device__ __forceinline__ void gelu_acc(float l, float r, float g, float be,
                                         float w, float rstd, float& acc) {
    // gelu_tanh(x) = x * sigmoid(1.5957691*(x + 0.044715 x^3))
    // q = log2(exp(-2y)) = x*(A*x^2+B), B = -2*log2e*0.79788456, A = B*0.044715
    float s = l + r;
    float x = fmaf(s * rstd, g, be);
    float x2 = x * x;
    float q = x * fmaf(-0.10294340f, x2, -2.30220935f);
    float eq = __builtin_amdgcn_exp2f(q);
    float ge = x * __builtin_amdgcn_rcpf(1.f + eq);
    acc = fmaf(ge, w, acc);
}

__global__ __launch_bounds__(256, 4) void k_pair(const float* __restrict__ W,
                                                 const float* __restrict__ var,
                                                 const float* __restrict__ gf,
                                                 const float* __restrict__ bef,
                                                 const float* __restrict__ wf,
                                                 const float* __restrict__ b2f,
                                                 float* __restrict__ out) {
    __shared__ float smem[4416];        // ls[0..2079] rs[2080..4159] rstd[4160..4415]
    float* ls = smem;                   // [16][130]
    float* rs = smem + 2080;            // [16][130]
    float* red = smem;                  // [16][257] overlay (4112 < 4160)
    float* rstd_s = smem + 4160;        // [256], p' = j*16+i

    // decode upper-triangle tile index b -> (I, J), I<=J, 32 tile-rows
    const int b = blockIdx.x;
    int I = (int)((65.0f - sqrtf(4225.0f - 8.0f * (float)b)) * 0.5f);
    if (I < 0) I = 0;
    if (I > 31) I = 31;
#define S_(i) (32 * (i) - ((i) * ((i)-1)) / 2)
    while (S_(I) > b) --I;
    while (S_(I + 1) <= b) ++I;
    const int J = I + (b - S_(I));
#undef S_

    const int t = threadIdx.x;
    const int l = t & 63, wv = t >> 6;
    const int pt = l & 15, s = l >> 4;
    const int pi = pt & 3, pj = pt >> 2;
    const int sigma = wv * 4 + s;
    const int i4 = pi * 4, j4 = pj * 4;
    const int Ibase = I * 16, Jbase = N_ + J * 16;

    // ================= pass A: cov =================
    float cv[16];
#pragma unroll
    for (int c = 0; c < 16; ++c) cv[c] = 0.f;
    for (int c = 0; c < 4; ++c) {
#pragma unroll
        for (int it = 0; it < 2; ++it) {
            int x = t + it * 256;
            int rr = x >> 5, q = x & 31;
            *(float4*)&ls[rr * 130 + q * 4] = *(const float4*)&W[(Ibase + rr) * D_ + c * 128 + q * 4];
            *(float4*)&rs[rr * 130 + q * 4] = *(const float4*)&W[(Jbase + rr) * D_ + c * 128 + q * 4];
        }
        __syncthreads();
#pragma unroll
        for (int mm = 0; mm < 2; ++mm) {
            const int off = 64 * mm + 4 * sigma;
            float4 lq[4], rq[4];
#pragma unroll
            for (int d = 0; d < 4; ++d) {
                lq[d] = *(float4*)&ls[(i4 + d) * 130 + off];
                rq[d] = *(float4*)&rs[(j4 + d) * 130 + off];
            }
#pragma unroll
            for (int di = 0; di < 4; ++di)
#pragma unroll
                for (int dj = 0; dj < 4; ++dj)
                    cv[di * 4 + dj] += lq[di].x * rq[dj].x + lq[di].y * rq[dj].y +
                                       lq[di].z * rq[dj].z + lq[di].w * rq[dj].w;
        }
        __syncthreads();
    }
#pragma unroll
    for (int di = 0; di < 4; ++di)
#pragma unroll
        for (int dj = 0; dj < 4; ++dj)
            red[sigma * 257 + (j4 + dj) * 16 + i4 + di] = cv[di * 4 + dj];
    __syncthreads();

    {   // thread t = pair p' = jj*16 + ii
        const int ii = t & 15, jj = t >> 4;
        float covsum = 0.f;
#pragma unroll
        for (int ss = 0; ss < 16; ++ss) covsum += red[ss * 257 + t];
        float varh = var[Ibase + ii] + var[Jbase + jj] + covsum * (2.f / D_) + 1e-5f;
        rstd_s[t] = rsqrtf(varh);
    }
    __syncthreads();

    // ================= pass B: gelu dot =================
    float rst[16];
#pragma unroll
    for (int di = 0; di < 4; ++di)
#pragma unroll
        for (int dj = 0; dj < 4; ++dj)
            rst[di * 4 + dj] = rstd_s[(j4 + dj) * 16 + i4 + di];
    float ac[16];
#pragma unroll
    for (int c = 0; c < 16; ++c) ac[c] = 0.f;
    for (int c = 0; c < 4; ++c) {
#pragma unroll
        for (int it = 0; it < 2; ++it) {
            int x = t + it * 256;
            int rr = x >> 5, q = x & 31;
            *(float4*)&ls[rr * 130 + q * 4] = *(const float4*)&W[(Ibase + rr) * D_ + c * 128 + q * 4];
            *(float4*)&rs[rr * 130 + q * 4] = *(const float4*)&W[(Jbase + rr) * D_ + c * 128 + q * 4];
        }
        __syncthreads();
#pragma unroll
        for (int mm = 0; mm < 2; ++mm) {
            const int off = 64 * mm + 4 * sigma;
            const int kg = c * 128 + off;
            float4 g4 = *(const float4*)&gf[kg];
            float4 be4 = *(const float4*)&bef[kg];
            float4 w4 = *(const float4*)&wf[kg];
            float4 lq[4], rq[4];
#pragma unroll
            for (int d = 0; d < 4; ++d) {
                lq[d] = *(float4*)&ls[(i4 + d) * 130 + off];
                rq[d] = *(float4*)&rs[(j4 + d) * 130 + off];
            }
#pragma unroll
            for (int di = 0; di < 4; ++di)
#pragma unroll
                for (int dj = 0; dj < 4; ++dj) {
                    float rr2 = rst[di * 4 + dj];
                    float& a = ac[di * 4 + dj];
                    gelu_acc(lq[di].x, rq[dj].x, g4.x, be4.x, w4.x, rr2, a);
                    gelu_acc(lq[di].y, rq[dj].y, g4.y, be4.y, w4.y, rr2, a);
                    gelu_acc(lq[di].z, rq[dj].z, g4.z, be4.z, w4.z, rr2, a);
                    gelu_acc(lq[di].w, rq[dj].w, g4.w, be4.w, w4.w, rr2, a);
                }
        }
        __syncthreads();
    }
#pragma unroll
    for (int di = 0; di < 4; ++di)
#pragma unroll
        for (int dj = 0; dj < 4; ++dj)
            red[sigma * 257 + (j4 + dj) * 16 + i4 + di] = ac[di * 4 + dj];
    __syncthreads();

    {   // finalize: thread t = pair (ii, jj)
        const int ii = t & 15, jj = t >> 4;
        float z = b2f[0];
#pragma unroll
        for (int ss = 0; ss < 16; ++ss) z += red[ss * 257 + t];
        float sg = __builtin_amdgcn_rcpf(1.f + __builtin_amdgcn_exp2f(-1.44269504f * z));
        const int gi = Ibase + ii, gj = J * 16 + jj;
        if (gi <= gj) {
            out[gi * N_ + gj] = sg;
            out[gj * N_ + gi] = sg;
        }
    }
}

extern "C" void kernel_launch(void* const* d_in, const int* in_sizes, int n_in,
                              void* d_out, int out_size, void* d_ws, size_t ws_size,
                              hipStream_t stream) {
    const float* E     = (const float*)d_in[0];
    const float* W1    = (const float*)d_in[1];
    const float* b1    = (const float*)d_in[2];
    const float* gamma = (const float*)d_in[3];
    const float* beta  = (const float*)d_in[4];
    const float* w2    = (const float*)d_in[5];
    const float* b2    = (const float*)d_in[6];
    float* out = (float*)d_out;

    float* F    = (float*)d_ws;
    float* lcrc = F;                  // [1024][512]: rows 0..511 lc, 512..1023 rc(+b1)
    float* var  = F + 1024 * 512;     // [1024]

    k_gemm<<<512, 256, 0, stream>>>(E, W1, b1, lcrc);
    k_center<<<1024, 256, 0, stream>>>(lcrc, var);
    k_pair<<<528, 256, 0, stream>>>(lcrc, var, gamma, beta, w2, b2, out);
}

// Round 8
// 154.824 us; speedup vs baseline: 1.1066x; 1.1066x over previous
//
#include <hip/hip_runtime.h>

// N=512, D=512 pairwise scorer, all f32.
// left = E@W1[:D]; right = E@W1[D:]+b1; h = left[i]+right[j]; LN(D); GELU; @W2+b2; sigmoid.
// LN stats decompose: var = var_l[i]+var_r[j]+2*cov(i,j), cov = (1/D) lc@rc^T (centered).
// Never materialize [N,N,D]. Upper-triangle 16x16 pair tiles, mirrored store.
//
// k_pair is LDS-BW-bound: 4x4 register blocking reads 4 B/gelu-element
// (vs 16 B for 2x2) -> ~11 us LDS floor. NO min-waves launch_bounds: forcing
// occupancy caps VGPR at 64 -> spills -> 92 MB scratch traffic (round 7).

#define N_ 512
#define D_ 512

// ---------------- K1: left/right GEMMs ----------------
// 512 blocks = 32 rowgrps (16 rows) x 16 ccgrps (64 combined cols of 1024).
// 256 thr: c-quad = t&15, row = t>>4. 8-deep global load pipeline per k-iter
// (8 independent dwordx4 in flight) to beat L2 latency at 2 blocks/CU.
__global__ __launch_bounds__(256) void k_gemm(const float* __restrict__ E,
                                              const float* __restrict__ W1,
                                              const float* __restrict__ b1,
                                              float* __restrict__ W /* [1024][512] */) {
    __shared__ float e[16 * 516];
    const int t = threadIdx.x;
    const int cc = (blockIdx.x & 15) * 64;     // combined col base
    const int r0 = (blockIdx.x >> 4) * 16;
    const int half = cc >> 9;
    const int c = (cc & 511) + (t & 15) * 4;
    const int r = t >> 4;

    for (int x = t; x < 16 * 128; x += 256) {
        int rr = x >> 7, q = x & 127;
        *(float4*)&e[rr * 516 + q * 4] = *(const float4*)&E[(r0 + rr) * D_ + q * 4];
    }
    __syncthreads();

    const float* __restrict__ wp = W1 + (half << 18) + c;
    float4 acc = {0.f, 0.f, 0.f, 0.f};
#pragma unroll 2
    for (int k = 0; k < D_; k += 8) {
        // issue all 10 loads up front (8 global dwordx4 + 2 LDS b128)
        float4 w0 = *(const float4*)(wp + ((k + 0) << 9));
        float4 w1 = *(const float4*)(wp + ((k + 1) << 9));
        float4 w2 = *(const float4*)(wp + ((k + 2) << 9));
        float4 w3 = *(const float4*)(wp + ((k + 3) << 9));
        float4 w4 = *(const float4*)(wp + ((k + 4) << 9));
        float4 w5 = *(const float4*)(wp + ((k + 5) << 9));
        float4 w6 = *(const float4*)(wp + ((k + 6) << 9));
        float4 w7 = *(const float4*)(wp + ((k + 7) << 9));
        float4 ea = *(float4*)&e[r * 516 + k];
        float4 eb = *(float4*)&e[r * 516 + k + 4];
        acc.x = fmaf(ea.x, w0.x, acc.x); acc.y = fmaf(ea.x, w0.y, acc.y);
        acc.z = fmaf(ea.x, w0.z, acc.z); acc.w = fmaf(ea.x, w0.w, acc.w);
        acc.x = fmaf(ea.y, w1.x, acc.x); acc.y = fmaf(ea.y, w1.y, acc.y);
        acc.z = fmaf(ea.y, w1.z, acc.z); acc.w = fmaf(ea.y, w1.w, acc.w);
        acc.x = fmaf(ea.z, w2.x, acc.x); acc.y = fmaf(ea.z, w2.y, acc.y);
        acc.z = fmaf(ea.z, w2.z, acc.z); acc.w = fmaf(ea.z, w2.w, acc.w);
        acc.x = fmaf(ea.w, w3.x, acc.x); acc.y = fmaf(ea.w, w3.y, acc.y);
        acc.z = fmaf(ea.w, w3.z, acc.z); acc.w = fmaf(ea.w, w3.w, acc.w);
        acc.x = fmaf(eb.x, w4.x, acc.x); acc.y = fmaf(eb.x, w4.y, acc.y);
        acc.z = fmaf(eb.x, w4.z, acc.z); acc.w = fmaf(eb.x, w4.w, acc.w);
        acc.x = fmaf(eb.y, w5.x, acc.x); acc.y = fmaf(eb.y, w5.y, acc.y);
        acc.z = fmaf(eb.y, w5.z, acc.z); acc.w = fmaf(eb.y, w5.w, acc.w);
        acc.x = fmaf(eb.z, w6.x, acc.x); acc.y = fmaf(eb.z, w6.y, acc.y);
        acc.z = fmaf(eb.z, w6.z, acc.z); acc.w = fmaf(eb.z, w6.w, acc.w);
        acc.x = fmaf(eb.w, w7.x, acc.x); acc.y = fmaf(eb.w, w7.y, acc.y);
        acc.z = fmaf(eb.w, w7.z, acc.z); acc.w = fmaf(eb.w, w7.w, acc.w);
    }
    if (half) {
        float4 bb = *(const float4*)(b1 + c);
        acc.x += bb.x; acc.y += bb.y; acc.z += bb.z; acc.w += bb.w;
    }
    *(float4*)(W + ((half << 9) + r0 + r) * D_ + c) = acc;
}

// ---------------- K2: center rows, per-row variance ----------------
__device__ __forceinline__ float block_sum(float v, float* sred, int t) {
#pragma unroll
    for (int off = 32; off > 0; off >>= 1) v += __shfl_xor(v, off, 64);
    int wave = t >> 6;
    if ((t & 63) == 0) sred[wave] = v;
    __syncthreads();
    float s = sred[0] + sred[1] + sred[2] + sred[3];
    __syncthreads();
    return s;
}

__global__ __launch_bounds__(256) void k_center(float* __restrict__ W,
                                                float* __restrict__ var) {
    __shared__ float sred[4];
    const int r = blockIdx.x, t = threadIdx.x;
    float* p = W + r * D_;
    float v0 = p[t], v1 = p[t + 256];
    float s = block_sum(v0 + v1, sred, t);
    float mean = s * (1.f / D_);
    float c0 = v0 - mean, c1 = v1 - mean;
    float ss = block_sum(c0 * c0 + c1 * c1, sred, t);
    p[t] = c0;
    p[t + 256] = c1;
    if (t == 0) var[r] = ss * (1.f / D_);
}

// ---------------- K3: fused cov -> rstd -> gelu-dot -> sigmoid ----------------
// 528 blocks = upper-triangle 16x16 pair tiles. 256 thr:
//   lane l = t&63: pt = l&15 (4x4 pair block: pi=pt&3, pj=pt>>2), s = l>>4.
//   k-slice sigma = (t>>6)*4 + s owns quads Q = 16m + sigma (m=0..7).
// LDS: ls/rs [16][130] (stride 130 = 2 mod 32: rows d,4+d,8+d,12+d -> 4 distinct
// bank groups). Chunked k=128. red[16][257] overlays ls/rs after each pass.
// ~17.7KB LDS, 16 chains/thread, ~100 VGPR (do NOT force occupancy).
__device__ __forceinline__ void gelu_acc(float l, float r, float g, float be,
                                         float w, float rstd, float& acc) {
    // gelu_tanh(x) = x * sigmoid(1.5957691*(x + 0.044715 x^3))
    // q = log2(exp(-2y)) = x*(A*x^2+B), B = -2*log2e*0.79788456, A = B*0.044715
    float s = l + r;
    float x = fmaf(s * rstd, g, be);
    float x2 = x * x;
    float q = x * fmaf(-0.10294340f, x2, -2.30220935f);
    float eq = __builtin_amdgcn_exp2f(q);
    float ge = x * __builtin_amdgcn_rcpf(1.f + eq);
    acc = fmaf(ge, w, acc);
}

__global__ __launch_bounds__(256) void k_pair(const float* __restrict__ W,
                                              const float* __restrict__ var,
                                              const float* __restrict__ gf,
                                              const float* __restrict__ bef,
                                              const float* __restrict__ wf,
                                              const float* __restrict__ b2f,
                                              float* __restrict__ out) {
    __shared__ float smem[4416];        // ls[0..2079] rs[2080..4159] rstd[4160..4415]
    float* ls = smem;                   // [16][130]
    float* rs = smem + 2080;            // [16][130]
    float* red = smem;                  // [16][257] overlay (4112 < 4160)
    float* rstd_s = smem + 4160;        // [256], p' = j*16+i

    // decode upper-triangle tile index b -> (I, J), I<=J, 32 tile-rows
    const int b = blockIdx.x;
    int I = (int)((65.0f - sqrtf(4225.0f - 8.0f * (float)b)) * 0.5f);
    if (I < 0) I = 0;
    if (I > 31) I = 31;
#define S_(i) (32 * (i) - ((i) * ((i)-1)) / 2)
    while (S_(I) > b) --I;
    while (S_(I + 1) <= b) ++I;
    const int J = I + (b - S_(I));
#undef S_

    const int t = threadIdx.x;
    const int l = t & 63, wv = t >> 6;
    const int pt = l & 15, s = l >> 4;
    const int pi = pt & 3, pj = pt >> 2;
    const int sigma = wv * 4 + s;
    const int i4 = pi * 4, j4 = pj * 4;
    const int Ibase = I * 16, Jbase = N_ + J * 16;

    // ================= pass A: cov =================
    float cv[16];
#pragma unroll
    for (int c = 0; c < 16; ++c) cv[c] = 0.f;
    for (int c = 0; c < 4; ++c) {
#pragma unroll
        for (int it = 0; it < 2; ++it) {
            int x = t + it * 256;
            int rr = x >> 5, q = x & 31;
            *(float4*)&ls[rr * 130 + q * 4] = *(const float4*)&W[(Ibase + rr) * D_ + c * 128 + q * 4];
            *(float4*)&rs[rr * 130 + q * 4] = *(const float4*)&W[(Jbase + rr) * D_ + c * 128 + q * 4];
        }
        __syncthreads();
#pragma unroll
        for (int mm = 0; mm < 2; ++mm) {
            const int off = 64 * mm + 4 * sigma;
            float4 lq[4], rq[4];
#pragma unroll
            for (int d = 0; d < 4; ++d) {
                lq[d] = *(float4*)&ls[(i4 + d) * 130 + off];
                rq[d] = *(float4*)&rs[(j4 + d) * 130 + off];
            }
#pragma unroll
            for (int di = 0; di < 4; ++di)
#pragma unroll
                for (int dj = 0; dj < 4; ++dj)
                    cv[di * 4 + dj] += lq[di].x * rq[dj].x + lq[di].y * rq[dj].y +
                                       lq[di].z * rq[dj].z + lq[di].w * rq[dj].w;
        }
        __syncthreads();
    }
#pragma unroll
    for (int di = 0; di < 4; ++di)
#pragma unroll
        for (int dj = 0; dj < 4; ++dj)
            red[sigma * 257 + (j4 + dj) * 16 + i4 + di] = cv[di * 4 + dj];
    __syncthreads();

    {   // thread t = pair p' = jj*16 + ii
        const int ii = t & 15, jj = t >> 4;
        float covsum = 0.f;
#pragma unroll
        for (int ss = 0; ss < 16; ++ss) covsum += red[ss * 257 + t];
        float varh = var[Ibase + ii] + var[Jbase + jj] + covsum * (2.f / D_) + 1e-5f;
        rstd_s[t] = rsqrtf(varh);
    }
    __syncthreads();

    // ================= pass B: gelu dot =================
    float rst[16];
#pragma unroll
    for (int di = 0; di < 4; ++di)
#pragma unroll
        for (int dj = 0; dj < 4; ++dj)
            rst[di * 4 + dj] = rstd_s[(j4 + dj) * 16 + i4 + di];
    float ac[16];
#pragma unroll
    for (int c = 0; c < 16; ++c) ac[c] = 0.f;
    for (int c = 0; c < 4; ++c) {
#pragma unroll
        for (int it = 0; it < 2; ++it) {
            int x = t + it * 256;
            int rr = x >> 5, q = x & 31;
            *(float4*)&ls[rr * 130 + q * 4] = *(const float4*)&W[(Ibase + rr) * D_ + c * 128 + q * 4];
            *(float4*)&rs[rr * 130 + q * 4] = *(const float4*)&W[(Jbase + rr) * D_ + c * 128 + q * 4];
        }
        __syncthreads();
#pragma unroll
        for (int mm = 0; mm < 2; ++mm) {
            const int off = 64 * mm + 4 * sigma;
            const int kg = c * 128 + off;
            float4 g4 = *(const float4*)&gf[kg];
            float4 be4 = *(const float4*)&bef[kg];
            float4 w4 = *(const float4*)&wf[kg];
            float4 lq[4], rq[4];
#pragma unroll
            for (int d = 0; d < 4; ++d) {
                lq[d] = *(float4*)&ls[(i4 + d) * 130 + off];
                rq[d] = *(float4*)&rs[(j4 + d) * 130 + off];
            }
#pragma unroll
            for (int di = 0; di < 4; ++di)
#pragma unroll
                for (int dj = 0; dj < 4; ++dj) {
                    float rr2 = rst[di * 4 + dj];
                    float& a = ac[di * 4 + dj];
                    gelu_acc(lq[di].x, rq[dj].x, g4.x, be4.x, w4.x, rr2, a);
                    gelu_acc(lq[di].y, rq[dj].y, g4.y, be4.y, w4.y, rr2, a);
                    gelu_acc(lq[di].z, rq[dj].z, g4.z, be4.z, w4.z, rr2, a);
                    gelu_acc(lq[di].w, rq[dj].w, g4.w, be4.w, w4.w, rr2, a);
                }
        }
        __syncthreads();
    }
#pragma unroll
    for (int di = 0; di < 4; ++di)
#pragma unroll
        for (int dj = 0; dj < 4; ++dj)
            red[sigma * 257 + (j4 + dj) * 16 + i4 + di] = ac[di * 4 + dj];
    __syncthreads();

    {   // finalize: thread t = pair (ii, jj)
        const int ii = t & 15, jj = t >> 4;
        float z = b2f[0];
#pragma unroll
        for (int ss = 0; ss < 16; ++ss) z += red[ss * 257 + t];
        float sg = __builtin_amdgcn_rcpf(1.f + __builtin_amdgcn_exp2f(-1.44269504f * z));
        const int gi = Ibase + ii, gj = J * 16 + jj;
        if (gi <= gj) {
            out[gi * N_ + gj] = sg;
            out[gj * N_ + gi] = sg;
        }
    }
}

extern "C" void kernel_launch(void* const* d_in, const int* in_sizes, int n_in,
                              void* d_out, int out_size, void* d_ws, size_t ws_size,
                              hipStream_t stream) {
    const float* E     = (const float*)d_in[0];
    const float* W1    = (const float*)d_in[1];
    const float* b1    = (const float*)d_in[2];
    const float* gamma = (const float*)d_in[3];
    const float* beta  = (const float*)d_in[4];
    const float* w2    = (const float*)d_in[5];
    const float* b2    = (const float*)d_in[6];
    float* out = (float*)d_out;

    float* F    = (float*)d_ws;
    float* lcrc = F;                  // [1024][512]: rows 0..511 lc, 512..1023 rc(+b1)
    float* var  = F + 1024 * 512;     // [1024]

    k_gemm<<<512, 256, 0, stream>>>(E, W1, b1, lcrc);
    k_center<<<1024, 256, 0, stream>>>(lcrc, var);
    k_pair<<<528, 256, 0, stream>>>(lcrc, var, gamma, beta, w2, b2, out);
}

// Round 10
// 147.230 us; speedup vs baseline: 1.1636x; 1.0516x over previous
//
#include <hip/hip_runtime.h>

// N=512, D=512 pairwise scorer, all f32.
// left = E@W1[:D]; right = E@W1[D:]+b1; h = left[i]+right[j]; LN(D); GELU; @W2+b2; sigmoid.
// LN stats decompose (raw-moment form, no centering pass needed):
//   mu_h = mu_l[i]+mu_r[j]; var_h = var_l+var_r+2*cov; cov = dot(l,r)/D - mu_l*mu_r.
// Never materialize [N,N,D]. Upper-triangle 16x16 pair tiles, mirrored store.
// TWO kernels only: gemm -> pair. k_pair: single full-512k staging (few
// barriers) + 4x4 register blocking (2 B/elem LDS) + shfl reductions.
// NO min-waves launch_bounds (round 7: forcing occupancy -> spills).
// ROUND 9 BUG (fixed): staging loop only covered 1/4 of the tile (2 its, q*16
// vs q*4 mismatch) -> uninitialized LDS -> NaN. Now 8 its x 256 thr = 2048 f4.

#define N_ 512
#define D_ 512
#define LSTR 522   // LDS row stride; 522 mod 32 = 10 -> rows {0,4,8,12}+d map to
                   // bank-quads {0,8,16,24}+x : all access phases conflict-free

// ---------------- K1: left/right GEMMs (raw, only b1 added) ----------------
// 1024 blocks = 128 rowgrps (4 rows) x 8 ccgrps (128 combined cols of 1024).
// 256 thr: cq = t&31 (col quad), row = (t>>5)&3, kh = t>>7 (k-split 2).
// 4 blocks/CU, 16 waves/CU, 8 dwordx4 in flight per thread.
__global__ __launch_bounds__(256) void k_gemm(const float* __restrict__ E,
                                              const float* __restrict__ W1,
                                              const float* __restrict__ b1,
                                              float* __restrict__ W /* [1024][512] raw */) {
    __shared__ float e[4 * 516];
    __shared__ float4 pacc[128];   // kh=1 partials: [row*32 + cq]
    const int t = threadIdx.x;
    const int ccgrp = blockIdx.x & 7;
    const int r0 = (blockIdx.x >> 3) * 4;
    const int cc = ccgrp * 128;
    const int half = cc >> 9;
    const int c = (cc & 511) + (t & 31) * 4;
    const int row = (t >> 5) & 3;
    const int kh = t >> 7;

    for (int x = t; x < 4 * 128; x += 256) {
        int rr = x >> 7, q = x & 127;
        *(float4*)&e[rr * 516 + q * 4] = *(const float4*)&E[(r0 + rr) * D_ + q * 4];
    }
    __syncthreads();

    const float* __restrict__ wp = W1 + (half << 18) + (kh << 17) + c;  // + kh*256*512
    const float* __restrict__ ep = e + row * 516 + kh * 256;
    float4 acc = {0.f, 0.f, 0.f, 0.f};
#pragma unroll 4
    for (int k = 0; k < 256; k += 8) {
        float4 w0 = *(const float4*)(wp + ((k + 0) << 9));
        float4 w1 = *(const float4*)(wp + ((k + 1) << 9));
        float4 w2 = *(const float4*)(wp + ((k + 2) << 9));
        float4 w3 = *(const float4*)(wp + ((k + 3) << 9));
        float4 w4 = *(const float4*)(wp + ((k + 4) << 9));
        float4 w5 = *(const float4*)(wp + ((k + 5) << 9));
        float4 w6 = *(const float4*)(wp + ((k + 6) << 9));
        float4 w7 = *(const float4*)(wp + ((k + 7) << 9));
        float4 ea = *(const float4*)(ep + k);
        float4 eb = *(const float4*)(ep + k + 4);
        acc.x = fmaf(ea.x, w0.x, acc.x); acc.y = fmaf(ea.x, w0.y, acc.y);
        acc.z = fmaf(ea.x, w0.z, acc.z); acc.w = fmaf(ea.x, w0.w, acc.w);
        acc.x = fmaf(ea.y, w1.x, acc.x); acc.y = fmaf(ea.y, w1.y, acc.y);
        acc.z = fmaf(ea.y, w1.z, acc.z); acc.w = fmaf(ea.y, w1.w, acc.w);
        acc.x = fmaf(ea.z, w2.x, acc.x); acc.y = fmaf(ea.z, w2.y, acc.y);
        acc.z = fmaf(ea.z, w2.z, acc.z); acc.w = fmaf(ea.z, w2.w, acc.w);
        acc.x = fmaf(ea.w, w3.x, acc.x); acc.y = fmaf(ea.w, w3.y, acc.y);
        acc.z = fmaf(ea.w, w3.z, acc.z); acc.w = fmaf(ea.w, w3.w, acc.w);
        acc.x = fmaf(eb.x, w4.x, acc.x); acc.y = fmaf(eb.x, w4.y, acc.y);
        acc.z = fmaf(eb.x, w4.z, acc.z); acc.w = fmaf(eb.x, w4.w, acc.w);
        acc.x = fmaf(eb.y, w5.x, acc.x); acc.y = fmaf(eb.y, w5.y, acc.y);
        acc.z = fmaf(eb.y, w5.z, acc.z); acc.w = fmaf(eb.y, w5.w, acc.w);
        acc.x = fmaf(eb.z, w6.x, acc.x); acc.y = fmaf(eb.z, w6.y, acc.y);
        acc.z = fmaf(eb.z, w6.z, acc.z); acc.w = fmaf(eb.z, w6.w, acc.w);
        acc.x = fmaf(eb.w, w7.x, acc.x); acc.y = fmaf(eb.w, w7.y, acc.y);
        acc.z = fmaf(eb.w, w7.z, acc.z); acc.w = fmaf(eb.w, w7.w, acc.w);
    }
    if (kh == 1) {
        pacc[row * 32 + (t & 31)] = acc;
    }
    __syncthreads();
    if (kh == 0) {
        float4 p = pacc[row * 32 + (t & 31)];
        acc.x += p.x; acc.y += p.y; acc.z += p.z; acc.w += p.w;
        if (half) {
            float4 bb = *(const float4*)(b1 + c);
            acc.x += bb.x; acc.y += bb.y; acc.z += bb.z; acc.w += bb.w;
        }
        *(float4*)(W + ((half << 9) + r0 + row) * D_ + c) = acc;
    }
}

// ------- K2: fused stats -> cov -> rstd -> gelu-dot -> sigmoid -------
// 528 blocks = upper-triangle 16x16 pair tiles. 256 thr:
//   lane l = t&63: pt = l&15 (4x4 pair block: i4=(pt&3)*4, j4=(pt>>2)*4), s=l>>4;
//   sigma = (t>>6)*4 + s owns k-quads {16m+sigma}, m=0..7 (32 k per pair).
// Full raw 512-k tiles staged ONCE; row stats from LDS; sigma-partials reduced
// by shfl_xor(16/32) then tiny LDS array. ~73.5KB LDS -> 2 blocks/CU.
__device__ __forceinline__ void gelu_acc(float l, float r, float g, float be,
                                         float w, float rstd, float m2, float& acc) {
    // u = (l+r-mu)*rstd = fma(l+r, rstd, m2), m2 = -mu*rstd
    // gelu_tanh(x) = x * sigmoid(1.5957691*(x + 0.044715 x^3))
    // q = log2(exp(-2y)) = x*(A*x^2+B), B = -2*log2e*0.79788456, A = B*0.044715
    float s = l + r;
    float u = fmaf(s, rstd, m2);
    float x = fmaf(u, g, be);
    float x2 = x * x;
    float q = x * fmaf(-0.10294340f, x2, -2.30220935f);
    float eq = __builtin_amdgcn_exp2f(q);
    float ge = x * __builtin_amdgcn_rcpf(1.f + eq);
    acc = fmaf(ge, w, acc);
}

__global__ __launch_bounds__(256) void k_pair(const float* __restrict__ W,
                                              const float* __restrict__ gf,
                                              const float* __restrict__ bef,
                                              const float* __restrict__ wf,
                                              const float* __restrict__ b2,
                                              float* __restrict__ out) {
    __shared__ float ls[16 * LSTR];
    __shared__ float rs[16 * LSTR];
    __shared__ float red4[4 * 272];     // [wv][pt*17 + c]
    __shared__ float mu_s[32], vv_s[32];
    __shared__ float rstd_s[256], m2_s[256];

    // decode upper-triangle tile index b -> (I, J), I<=J, 32 tile-rows
    const int b = blockIdx.x;
    int I = (int)((65.0f - sqrtf(4225.0f - 8.0f * (float)b)) * 0.5f);
    if (I < 0) I = 0;
    if (I > 31) I = 31;
#define S_(i) (32 * (i) - ((i) * ((i)-1)) / 2)
    while (S_(I) > b) --I;
    while (S_(I + 1) <= b) ++I;
    const int J = I + (b - S_(I));
#undef S_

    const int t = threadIdx.x;
    const int l = t & 63, wv = t >> 6;
    const int pt = l & 15, s = l >> 4;
    const int sigma = wv * 4 + s;
    const int i4 = (pt & 3) * 4, j4 = (pt >> 2) * 4;
    const int Ibase = I * 16, Jbase = N_ + J * 16;

    // ---- stage full raw tiles once: 16 rows x 128 quads each ----
#pragma unroll
    for (int it = 0; it < 8; ++it) {
        int x = t + it * 256;
        int rr = x >> 7, q = x & 127;
        *(float4*)&ls[rr * LSTR + q * 4] = *(const float4*)&W[(Ibase + rr) * D_ + q * 4];
        *(float4*)&rs[rr * LSTR + q * 4] = *(const float4*)&W[(Jbase + rr) * D_ + q * 4];
    }
    __syncthreads();

    // ---- per-row stats from LDS: row = t>>3 (0..31), q = t&7 ----
    {
        const int row = t >> 3, q = t & 7;
        const float* src = (row < 16) ? &ls[row * LSTR] : &rs[(row - 16) * LSTR];
        float sum = 0.f, ss = 0.f;
#pragma unroll
        for (int j = 0; j < 16; ++j) {
            float4 v = *(const float4*)&src[j * 32 + q * 4];
            sum += v.x + v.y + v.z + v.w;
            ss += v.x * v.x + v.y * v.y + v.z * v.z + v.w * v.w;
        }
#pragma unroll
        for (int off = 1; off < 8; off <<= 1) {
            sum += __shfl_xor(sum, off, 64);
            ss += __shfl_xor(ss, off, 64);
        }
        if (q == 0) {
            float mu = sum * (1.f / D_);
            mu_s[row] = mu;
            vv_s[row] = ss * (1.f / D_) - mu * mu;
        }
    }
    // ---- pass A: raw dot partials (4x4, this sigma's 32 k) ----
    float cv[16];
#pragma unroll
    for (int c = 0; c < 16; ++c) cv[c] = 0.f;
#pragma unroll
    for (int mm = 0; mm < 8; ++mm) {
        const int off = 64 * mm + 4 * sigma;
        float4 lq[4], rq[4];
#pragma unroll
        for (int d = 0; d < 4; ++d) {
            lq[d] = *(float4*)&ls[(i4 + d) * LSTR + off];
            rq[d] = *(float4*)&rs[(j4 + d) * LSTR + off];
        }
#pragma unroll
        for (int di = 0; di < 4; ++di)
#pragma unroll
            for (int dj = 0; dj < 4; ++dj)
                cv[di * 4 + dj] += lq[di].x * rq[dj].x + lq[di].y * rq[dj].y +
                                   lq[di].z * rq[dj].z + lq[di].w * rq[dj].w;
    }
    // reduce over s (lanes ^16, ^32) in-register
#pragma unroll
    for (int c = 0; c < 16; ++c) {
        cv[c] += __shfl_xor(cv[c], 16, 64);
        cv[c] += __shfl_xor(cv[c], 32, 64);
    }
    if (l < 16) {
#pragma unroll
        for (int c = 0; c < 16; ++c) red4[wv * 272 + pt * 17 + c] = cv[c];
    }
    __syncthreads();

    // ---- per-pair rstd/m2: thread t = (ii = t&15, jj = t>>4) ----
    {
        const int ii = t & 15, jj = t >> 4;
        const int ppt = (ii >> 2) + ((jj >> 2) << 2);
        const int cc2 = (ii & 3) * 4 + (jj & 3);
        float dot = red4[0 * 272 + ppt * 17 + cc2] + red4[1 * 272 + ppt * 17 + cc2] +
                    red4[2 * 272 + ppt * 17 + cc2] + red4[3 * 272 + ppt * 17 + cc2];
        float mui = mu_s[ii], muj = mu_s[16 + jj];
        float cov = dot * (1.f / D_) - mui * muj;
        float varh = vv_s[ii] + vv_s[16 + jj] + 2.f * cov + 1e-5f;
        float rstd = rsqrtf(varh);
        rstd_s[t] = rstd;
        m2_s[t] = -(mui + muj) * rstd;
    }
    __syncthreads();

    // ---- pass B: gelu dot ----
    float rstA[16], m2A[16];
#pragma unroll
    for (int di = 0; di < 4; ++di)
#pragma unroll
        for (int dj = 0; dj < 4; ++dj) {
            int p = (j4 + dj) * 16 + (i4 + di);
            rstA[di * 4 + dj] = rstd_s[p];
            m2A[di * 4 + dj] = m2_s[p];
        }
    float ac[16];
#pragma unroll
    for (int c = 0; c < 16; ++c) ac[c] = 0.f;
#pragma unroll 2
    for (int mm = 0; mm < 8; ++mm) {
        const int off = 64 * mm + 4 * sigma;
        float4 g4 = *(const float4*)&gf[off];
        float4 be4 = *(const float4*)&bef[off];
        float4 w4 = *(const float4*)&wf[off];
        float4 lq[4], rq[4];
#pragma unroll
        for (int d = 0; d < 4; ++d) {
            lq[d] = *(float4*)&ls[(i4 + d) * LSTR + off];
            rq[d] = *(float4*)&rs[(j4 + d) * LSTR + off];
        }
#pragma unroll
        for (int di = 0; di < 4; ++di)
#pragma unroll
            for (int dj = 0; dj < 4; ++dj) {
                float rr2 = rstA[di * 4 + dj], mm2 = m2A[di * 4 + dj];
                float& a = ac[di * 4 + dj];
                gelu_acc(lq[di].x, rq[dj].x, g4.x, be4.x, w4.x, rr2, mm2, a);
                gelu_acc(lq[di].y, rq[dj].y, g4.y, be4.y, w4.y, rr2, mm2, a);
                gelu_acc(lq[di].z, rq[dj].z, g4.z, be4.z, w4.z, rr2, mm2, a);
                gelu_acc(lq[di].w, rq[dj].w, g4.w, be4.w, w4.w, rr2, mm2, a);
            }
    }
#pragma unroll
    for (int c = 0; c < 16; ++c) {
        ac[c] += __shfl_xor(ac[c], 16, 64);
        ac[c] += __shfl_xor(ac[c], 32, 64);
    }
    __syncthreads();   // red4 reuse
    if (l < 16) {
#pragma unroll
        for (int c = 0; c < 16; ++c) red4[wv * 272 + pt * 17 + c] = ac[c];
    }
    __syncthreads();

    {   // finalize: thread t = pair (ii, jj)
        const int ii = t & 15, jj = t >> 4;
        const int ppt = (ii >> 2) + ((jj >> 2) << 2);
        const int cc2 = (ii & 3) * 4 + (jj & 3);
        float z = red4[0 * 272 + ppt * 17 + cc2] + red4[1 * 272 + ppt * 17 + cc2] +
                  red4[2 * 272 + ppt * 17 + cc2] + red4[3 * 272 + ppt * 17 + cc2] + b2[0];
        float sg = __builtin_amdgcn_rcpf(1.f + __builtin_amdgcn_exp2f(-1.44269504f * z));
        const int gi = Ibase + ii, gj = J * 16 + jj;
        if (gi <= gj) {
            out[gi * N_ + gj] = sg;
            out[gj * N_ + gi] = sg;
        }
    }
}

extern "C" void kernel_launch(void* const* d_in, const int* in_sizes, int n_in,
                              void* d_out, int out_size, void* d_ws, size_t ws_size,
                              hipStream_t stream) {
    const float* E     = (const float*)d_in[0];
    const float* W1    = (const float*)d_in[1];
    const float* b1    = (const float*)d_in[2];
    const float* gamma = (const float*)d_in[3];
    const float* beta  = (const float*)d_in[4];
    const float* w2    = (const float*)d_in[5];
    const float* b2    = (const float*)d_in[6];
    float* out = (float*)d_out;

    float* W = (float*)d_ws;   // [1024][512] raw: rows 0..511 left, 512..1023 right+b1

    k_gemm<<<1024, 256, 0, stream>>>(E, W1, b1, W);
    k_pair<<<528, 256, 0, stream>>>(W, gamma, beta, w2, b2, out);
}